// Round 6
// baseline (185.707 us; speedup 1.0000x reference)
//
#include <hip/hip_runtime.h>
#include <hip/hip_bf16.h>

#define NPTS   2048
#define IDIM   16
#define HDIM   32
#define CUTSN  8
#define EPSV   1e-5f
#define PSCALE 0.07856742013183862f   /* 1/(sqrt(2)*9) */

typedef __bf16 bf16x8 __attribute__((ext_vector_type(8)));
typedef float  f32x16 __attribute__((ext_vector_type(16)));

__device__ __forceinline__ float leaky(float x) { return x >= 0.f ? x : 0.2f * x; }

/* ------- two-layer MLP (per-row) + per-block GroupNorm partial sums -------
 * 8 blocks x 256 threads, one row per thread. partials layout (64 floats):
 * [g*8 + block] = group sums, [32 + g*8 + block] = group sumsq.
 * Optionally zeroes zbuf (the pairwise accumulator) - same rows. */
template <int K>
__global__ __launch_bounds__(256) void net2_kernel(
    const float* __restrict__ xin,
    const float* __restrict__ W1, const float* __restrict__ b1,
    const float* __restrict__ W2, const float* __restrict__ b2,
    float* __restrict__ out, float* __restrict__ partials,
    float* __restrict__ zbuf)
{
    const int t = threadIdx.x;
    const int i = blockIdx.x * 256 + t;
    if (zbuf) {
#pragma unroll
        for (int e = 0; e < 8; ++e)
            *(float4*)&zbuf[i * HDIM + e * 4] = make_float4(0.f, 0.f, 0.f, 0.f);
    }
    float x[K];
#pragma unroll
    for (int k = 0; k < K; ++k) x[k] = xin[i * K + k];

    float y[HDIM];
#pragma unroll
    for (int h = 0; h < HDIM; ++h) {
        float v = b1[h];
#pragma unroll
        for (int k = 0; k < K; ++k) v = fmaf(x[k], W1[h * K + k], v);
        y[h] = leaky(v);
    }
    float ps[4]  = {0.f, 0.f, 0.f, 0.f};
    float pss[4] = {0.f, 0.f, 0.f, 0.f};
#pragma unroll
    for (int h = 0; h < HDIM; ++h) {
        float v = b2[h];
#pragma unroll
        for (int k = 0; k < HDIM; ++k) v = fmaf(y[k], W2[h * HDIM + k], v);
        v = leaky(v);
        out[i * HDIM + h] = v;
        const int g = h >> 3;                 /* compile-time after unroll */
        ps[g] += v; pss[g] = fmaf(v, v, pss[g]);
    }
#pragma unroll
    for (int off = 32; off; off >>= 1) {
#pragma unroll
        for (int g = 0; g < 4; ++g) {
            ps[g]  += __shfl_down(ps[g],  off, 64);
            pss[g] += __shfl_down(pss[g], off, 64);
        }
    }
    __shared__ float lred[4][8];
    const int wv = t >> 6, ln = t & 63;
    if (ln == 0) {
#pragma unroll
        for (int g = 0; g < 4; ++g) { lred[wv][g] = ps[g]; lred[wv][4 + g] = pss[g]; }
    }
    __syncthreads();
    if (t < 8) {
        const float v = lred[0][t] + lred[1][t] + lred[2][t] + lred[3][t];
        partials[t * 8 + blockIdx.x] = v;
    }
}

/* ------- GroupNorm apply (final output): reduces block-partials inline ------- */
__global__ __launch_bounds__(256) void gn_apply_kernel(
    const float* __restrict__ x, const float* __restrict__ partials,
    const float* __restrict__ gw, const float* __restrict__ gb,
    float* __restrict__ out)
{
    const int idx = blockIdx.x * 256 + threadIdx.x;   /* < NPTS*HDIM */
    const int c = idx & (HDIM - 1);
    const int g = c >> 3;
    float s = 0.f, q = 0.f;
#pragma unroll
    for (int b = 0; b < 8; ++b) {
        s += partials[g * 8 + b];
        q += partials[32 + g * 8 + b];
    }
    const float inv = 1.f / (8.f * NPTS);
    const float mu = s * inv;
    const float rs = rsqrtf(q * inv - mu * mu + EPSV);
    out[idx] = fmaf((x[idx] - mu) * rs, gw[c], gb[c]);
}

/* =================== N^2 pairwise via MFMA ===================
 * grid (8, 64): x -> 256-j group (8 waves x 32 j), y -> 32-i chunk.
 * Each wave owns one 32-j tile and loops over the block's 32 i's.
 * Per (i, j-tile): one v_mfma_f32_32x32x16_bf16 computes
 *   D[j][h] = U[j][k] * A2e[k][h],  K-packing: k=0..7 = w*relu(cut_c)
 *   (window folded: w>0 so w*relu(z)=relu(w*z)), k=8 = w vs B-row B2[h]
 *   (bias slot), k>8 = 0.  Post: acc_ih += relu(D)*f_jh  (f in 16 regs/lane,
 *   loaded once per wave with GroupNorm applied inline).
 * A-frag: row=lane&31, k=8*(lane>>5)+e.  B-frag: col=lane&31, same k.
 * D: col=lane&31, row=(reg&3)+8*(reg>>2)+4*(lane>>5)   [m74/m101].
 * cut_c = M_ic . diff + B1_c with M_ic = A1_c @ nuv_i precomputed per i
 * into LDS (kills the 9-FMA local-coord step per pair).
 * i-loop is "#pragma unroll 1" and all register arrays use static indices
 * (rule #20); no min-occupancy bound (spill lessons, rounds 2-4). */
__global__ __launch_bounds__(512, 1) void pairwise_kernel(
    const float* __restrict__ points, const float* __restrict__ nuv,
    const float* __restrict__ A1, const float* __restrict__ B1,
    const float* __restrict__ A2, const float* __restrict__ B2,
    const float* __restrict__ traw, const float* __restrict__ partials,
    const float* __restrict__ gw, const float* __restrict__ gb,
    float* __restrict__ fout)
{
    const int t     = threadIdx.x;
    const int lane  = t & 63;
    const int wave  = __builtin_amdgcn_readfirstlane(t >> 6);
    const int h     = lane & 31;          /* B/D column; also local j for A-frag */
    const int khalf = lane >> 5;
    const int ibase = blockIdx.y * 32;
    const int jt0   = blockIdx.x * 256 + wave * 32;

    __shared__ __align__(16) float4 sIM[32][8];  /* {Mx,My,Mz,B1_c} per (i,c) */
    __shared__ __align__(16) float  sIP[32][8];  /* pi*s(3), ni(3), pad(2) */
    __shared__ float sacc[32][32];               /* fout tile accumulator */

    /* ---- stage i-side ---- */
    if (t < 256) {
        const int il = t >> 3, c = t & 7;
        const int i = ibase + il;
        float m0 = 0.f, m1 = 0.f, m2 = 0.f;
#pragma unroll
        for (int a = 0; a < 3; ++a) {
            const float wA = A1[c * 3 + a];
            m0 = fmaf(wA, nuv[i * 9 + a * 3 + 0], m0);
            m1 = fmaf(wA, nuv[i * 9 + a * 3 + 1], m1);
            m2 = fmaf(wA, nuv[i * 9 + a * 3 + 2], m2);
        }
        sIM[il][c] = make_float4(m0, m1, m2, B1[c]);
    }
    if (t < 32) {
        const int i = ibase + t;
        sIP[t][0] = points[i * 3 + 0] * PSCALE;
        sIP[t][1] = points[i * 3 + 1] * PSCALE;
        sIP[t][2] = points[i * 3 + 2] * PSCALE;
        sIP[t][3] = nuv[i * 9 + 0];
        sIP[t][4] = nuv[i * 9 + 1];
        sIP[t][5] = nuv[i * 9 + 2];
        sIP[t][6] = 0.f; sIP[t][7] = 0.f;
    }
    ((float*)sacc)[t]       = 0.f;
    ((float*)sacc)[t + 512] = 0.f;

    /* ---- per-lane j-side (loaded once) ---- */
    const int j = jt0 + h;
    const float pjx = points[j * 3 + 0] * PSCALE;
    const float pjy = points[j * 3 + 1] * PSCALE;
    const float pjz = points[j * 3 + 2] * PSCALE;
    const float njx = nuv[j * 9 + 0], njy = nuv[j * 9 + 1], njz = nuv[j * 9 + 2];

    /* ---- constant B fragment: A2e[k][h] ---- */
    bf16x8 bfrag;
#pragma unroll
    for (int e = 0; e < 8; ++e) {
        const float bv = (khalf == 0) ? A2[h * 8 + e] : (e == 0 ? B2[h] : 0.f);
        bfrag[e] = (__bf16)bv;
    }

    /* ---- GroupNorm-on-the-fly f registers (16 per lane) ---- */
    const int g4 = h >> 3;
    float s = 0.f, q = 0.f;
#pragma unroll
    for (int b = 0; b < 8; ++b) {
        s += partials[g4 * 8 + b];
        q += partials[32 + g4 * 8 + b];
    }
    const float inv = 1.f / (8.f * NPTS);
    const float mu = s * inv;
    const float rs = rsqrtf(q * inv - mu * mu + EPSV);
    const float alpha = rs * gw[h];
    const float gamma = fmaf(-mu, alpha, gb[h]);
    float freg[16];
#pragma unroll
    for (int r = 0; r < 16; ++r) {
        const int jr = (r & 3) + 8 * (r >> 2) + 4 * khalf;  /* D row for reg r */
        freg[r] = fmaf(traw[(jt0 + jr) * HDIM + h], alpha, gamma);
    }

    f32x16 czero;
#pragma unroll
    for (int e = 0; e < 16; ++e) czero[e] = 0.f;

    __syncthreads();

    /* ---- main i-loop ---- */
#pragma unroll 1
    for (int il = 0; il < 32; ++il) {
        const float4 ip0 = *(const float4*)&sIP[il][0];  /* pix,piy,piz,nix */
        const float4 ip1 = *(const float4*)&sIP[il][4];  /* niy,niz,-,- */
        const float dx = pjx - ip0.x, dy = pjy - ip0.y, dz = pjz - ip0.z;
        const float sq = fmaf(dx, dx, fmaf(dy, dy, dz * dz));
        const float dt = fmaf(ip0.w, njx, fmaf(ip1.x, njy, ip1.y * njz));
        const float tt = 2.f - dt;
        const float wv = __expf(-sq * tt * tt);

        float u[8];
#pragma unroll
        for (int c = 0; c < 8; ++c) {
            const float4 m = sIM[il][c];
            const float cut = fmaf(m.x, dx, fmaf(m.y, dy, fmaf(m.z, dz, m.w)));
            u[c] = wv * fmaxf(cut, 0.f);
        }
        bf16x8 afrag;
        afrag[0] = (__bf16)(khalf == 0 ? u[0] : wv);
#pragma unroll
        for (int e = 1; e < 8; ++e)
            afrag[e] = (__bf16)(khalf == 0 ? u[e] : 0.f);

        const f32x16 d = __builtin_amdgcn_mfma_f32_32x32x16_bf16(
            afrag, bfrag, czero, 0, 0, 0);

        float p0 = 0.f, p1 = 0.f;
#pragma unroll
        for (int r = 0; r < 16; r += 2) {
            p0 = fmaf(fmaxf(d[r],     0.f), freg[r],     p0);
            p1 = fmaf(fmaxf(d[r + 1], 0.f), freg[r + 1], p1);
        }
        atomicAdd(&sacc[il][h], p0 + p1);
    }

    __syncthreads();

    /* ---- flush tile to global ---- */
    {
        const int cell = t * 2;
        const int il0 = cell >> 5, h0 = cell & 31;
        atomicAdd(&fout[(ibase + il0) * HDIM + h0],     sacc[il0][h0]);
        atomicAdd(&fout[(ibase + il0) * HDIM + h0 + 1], sacc[il0][h0 + 1]);
    }
}

extern "C" void kernel_launch(void* const* d_in, const int* in_sizes, int n_in,
                              void* d_out, int out_size, void* d_ws, size_t ws_size,
                              hipStream_t stream)
{
    const float* points   = (const float*)d_in[0];
    const float* nuv      = (const float*)d_in[1];
    const float* features = (const float*)d_in[2];
    const float* W_in1    = (const float*)d_in[3];
    const float* b_in1    = (const float*)d_in[4];
    const float* W_in2    = (const float*)d_in[5];
    const float* b_in2    = (const float*)d_in[6];
    const float* g_in_w   = (const float*)d_in[7];
    const float* g_in_b   = (const float*)d_in[8];
    const float* A1       = (const float*)d_in[9];
    const float* A2       = (const float*)d_in[10];
    const float* W_out1   = (const float*)d_in[11];
    const float* b_out1   = (const float*)d_in[12];
    const float* W_out2   = (const float*)d_in[13];
    const float* b_out2   = (const float*)d_in[14];
    const float* g_out_w  = (const float*)d_in[15];
    const float* g_out_b  = (const float*)d_in[16];
    const float* B1       = (const float*)d_in[17];
    const float* B2       = (const float*)d_in[18];

    float* ws    = (float*)d_ws;
    float* t2a   = ws;               /* N*H raw net_in output */
    float* t2b   = ws + 65536;       /* N*H raw net_out output */
    float* fout  = ws + 131072;      /* N*H pairwise accumulator */
    float* part1 = ws + 196608;      /* 64 floats */
    float* part2 = ws + 196672;      /* 64 floats */
    float* out   = (float*)d_out;

    /* net_in (+stats partials, + zero fout) */
    net2_kernel<IDIM><<<dim3(NPTS / 256), dim3(256), 0, stream>>>(
        features, W_in1, b_in1, W_in2, b_in2, t2a, part1, fout);

    /* all-pairs interaction (GroupNorm of f applied on the fly) */
    pairwise_kernel<<<dim3(NPTS / 256, NPTS / 32), dim3(512), 0, stream>>>(
        points, nuv, A1, B1, A2, B2, t2a, part1, g_in_w, g_in_b, fout);

    /* net_out (+stats partials), then final normalize -> out */
    net2_kernel<HDIM><<<dim3(NPTS / 256), dim3(256), 0, stream>>>(
        fout, W_out1, b_out1, W_out2, b_out2, t2b, part2, nullptr);
    gn_apply_kernel<<<dim3(NPTS * HDIM / 256), dim3(256), 0, stream>>>(
        t2b, part2, g_out_w, g_out_b, out);
}

// Round 7
// 178.668 us; speedup vs baseline: 1.0394x; 1.0394x over previous
//
#include <hip/hip_runtime.h>
#include <hip/hip_bf16.h>

#define NPTS   2048
#define IDIM   16
#define HDIM   32
#define CUTSN  8
#define EPSV   1e-5f
#define PSCALE 0.07856742013183862f   /* 1/(sqrt(2)*9) */
#define ICH    16                     /* i-rows per block chunk */
#define IPK    48                     /* floats per ipack row (192B aligned) */

typedef __bf16 bf16x8 __attribute__((ext_vector_type(8)));
typedef float  f32x16 __attribute__((ext_vector_type(16)));

__device__ __forceinline__ float leaky(float x) { return x >= 0.f ? x : 0.2f * x; }

/* ------- two-layer MLP (per-row) + GroupNorm partial sums (+ipack/zero) -------
 * 8 blocks x 256 threads, one row per thread. partials layout (64 floats):
 * [g*8 + block] = group sums, [32 + g*8 + block] = group sumsq.
 * When ipack != nullptr also emits the pairwise i-side pack:
 *   [0..31] 8 x {Mx,My,Mz,B1_c} with M_c = A1_c @ nuv_i, [32..37] {p*s, n}. */
template <int K>
__global__ __launch_bounds__(256) void net2_kernel(
    const float* __restrict__ xin,
    const float* __restrict__ W1, const float* __restrict__ b1,
    const float* __restrict__ W2, const float* __restrict__ b2,
    float* __restrict__ out, float* __restrict__ partials,
    float* __restrict__ zbuf,
    const float* __restrict__ points, const float* __restrict__ nuv,
    const float* __restrict__ A1, const float* __restrict__ B1,
    float* __restrict__ ipack)
{
    const int t = threadIdx.x;
    const int i = blockIdx.x * 256 + t;
    if (zbuf) {
#pragma unroll
        for (int e = 0; e < 8; ++e)
            *(float4*)&zbuf[i * HDIM + e * 4] = make_float4(0.f, 0.f, 0.f, 0.f);
    }
    if (ipack) {
        float* ip = ipack + i * IPK;
#pragma unroll
        for (int c = 0; c < 8; ++c) {
            float m0 = 0.f, m1 = 0.f, m2 = 0.f;
#pragma unroll
            for (int a = 0; a < 3; ++a) {
                const float wA = A1[c * 3 + a];
                m0 = fmaf(wA, nuv[i * 9 + a * 3 + 0], m0);
                m1 = fmaf(wA, nuv[i * 9 + a * 3 + 1], m1);
                m2 = fmaf(wA, nuv[i * 9 + a * 3 + 2], m2);
            }
            *(float4*)&ip[c * 4] = make_float4(m0, m1, m2, B1[c]);
        }
        *(float4*)&ip[32] = make_float4(points[i * 3 + 0] * PSCALE,
                                        points[i * 3 + 1] * PSCALE,
                                        points[i * 3 + 2] * PSCALE,
                                        nuv[i * 9 + 0]);
        *(float4*)&ip[36] = make_float4(nuv[i * 9 + 1], nuv[i * 9 + 2], 0.f, 0.f);
        *(float4*)&ip[40] = make_float4(0.f, 0.f, 0.f, 0.f);
        *(float4*)&ip[44] = make_float4(0.f, 0.f, 0.f, 0.f);
    }

    float x[K];
#pragma unroll
    for (int k = 0; k < K; ++k) x[k] = xin[i * K + k];

    float y[HDIM];
#pragma unroll
    for (int h = 0; h < HDIM; ++h) {
        float v = b1[h];
#pragma unroll
        for (int k = 0; k < K; ++k) v = fmaf(x[k], W1[h * K + k], v);
        y[h] = leaky(v);
    }
    float ps[4]  = {0.f, 0.f, 0.f, 0.f};
    float pss[4] = {0.f, 0.f, 0.f, 0.f};
#pragma unroll
    for (int h = 0; h < HDIM; ++h) {
        float v = b2[h];
#pragma unroll
        for (int k = 0; k < HDIM; ++k) v = fmaf(y[k], W2[h * HDIM + k], v);
        v = leaky(v);
        out[i * HDIM + h] = v;
        const int g = h >> 3;                 /* compile-time after unroll */
        ps[g] += v; pss[g] = fmaf(v, v, pss[g]);
    }
#pragma unroll
    for (int off = 32; off; off >>= 1) {
#pragma unroll
        for (int g = 0; g < 4; ++g) {
            ps[g]  += __shfl_down(ps[g],  off, 64);
            pss[g] += __shfl_down(pss[g], off, 64);
        }
    }
    __shared__ float lred[4][8];
    const int wv = t >> 6, ln = t & 63;
    if (ln == 0) {
#pragma unroll
        for (int g = 0; g < 4; ++g) { lred[wv][g] = ps[g]; lred[wv][4 + g] = pss[g]; }
    }
    __syncthreads();
    if (t < 8) {
        const float v = lred[0][t] + lred[1][t] + lred[2][t] + lred[3][t];
        partials[t * 8 + blockIdx.x] = v;
    }
}

/* ------- GroupNorm apply (final output): reduces block-partials inline ------- */
__global__ __launch_bounds__(256) void gn_apply_kernel(
    const float* __restrict__ x, const float* __restrict__ partials,
    const float* __restrict__ gw, const float* __restrict__ gb,
    float* __restrict__ out)
{
    const int idx = blockIdx.x * 256 + threadIdx.x;   /* < NPTS*HDIM */
    const int c = idx & (HDIM - 1);
    const int g = c >> 3;
    float s = 0.f, q = 0.f;
#pragma unroll
    for (int b = 0; b < 8; ++b) {
        s += partials[g * 8 + b];
        q += partials[32 + g * 8 + b];
    }
    const float inv = 1.f / (8.f * NPTS);
    const float mu = s * inv;
    const float rs = rsqrtf(q * inv - mu * mu + EPSV);
    out[idx] = fmaf((x[idx] - mu) * rs, gw[c], gb[c]);
}

/* =================== N^2 pairwise via MFMA, scalar-pipe i-side ===============
 * grid (8, 128): x -> 256-j group (8 waves x 32 j), y -> 16-i chunk.
 * Wave owns a 32-j tile; loops its chunk's 16 i's, 2-deep software-pipelined.
 * i-side data comes from ipack via WAVE-UNIFORM addresses -> s_load batches
 * (scalar pipe; no VALU/LDS issue). j-side is per-lane registers, loaded once.
 * Per (i, j-tile): one v_mfma_f32_32x32x16_bf16:
 *   D[j][h] = U[j][k] * A2e[k][h]; k=0..7 = w*relu(cut_c) (window folded,
 *   w>0), k=8 = w against B2[h] (bias slot), k>8 = 0.
 * A-frag row=lane&31, k=8*(lane>>5)+e; D col=lane&31,
 * row=(reg&3)+8*(reg>>2)+4*(lane>>5)  [verified rounds 6].
 * Register arrays use ONLY static indices (rule #20); LDS acc addressed at
 * runtime (address arithmetic is fine). launch_bounds(512,1): VGPR cap 256
 * (spill lessons rounds 2-4). */
__global__ __launch_bounds__(512, 1) void pairwise_kernel(
    const float* __restrict__ points, const float* __restrict__ nuv,
    const float* __restrict__ A2, const float* __restrict__ B2,
    const float* __restrict__ ipack,
    const float* __restrict__ traw, const float* __restrict__ partials,
    const float* __restrict__ gw, const float* __restrict__ gb,
    float* __restrict__ fout)
{
    const int t     = threadIdx.x;
    const int lane  = t & 63;
    const int wave  = __builtin_amdgcn_readfirstlane(t >> 6);
    const int h     = lane & 31;          /* B/D column; local j for A-frag */
    const int khalf = lane >> 5;
    const int ibase = blockIdx.y * ICH;
    const int jt0   = blockIdx.x * 256 + wave * 32;

    __shared__ float sacc[ICH][32];       /* 2 KB tile accumulator */
    if (t < ICH * 32) ((float*)sacc)[t] = 0.f;

    /* ---- per-lane j-side (loaded once) ---- */
    const int j = jt0 + h;
    const float pjx = points[j * 3 + 0] * PSCALE;
    const float pjy = points[j * 3 + 1] * PSCALE;
    const float pjz = points[j * 3 + 2] * PSCALE;
    const float njx = nuv[j * 9 + 0], njy = nuv[j * 9 + 1], njz = nuv[j * 9 + 2];

    /* ---- constant B fragment: A2e[k][h] ---- */
    bf16x8 bfrag;
#pragma unroll
    for (int e = 0; e < 8; ++e) {
        const float bv = (khalf == 0) ? A2[h * 8 + e] : (e == 0 ? B2[h] : 0.f);
        bfrag[e] = (__bf16)bv;
    }

    /* ---- GroupNorm-on-the-fly f registers (16 per lane) ---- */
    const int g4 = h >> 3;
    float s = 0.f, q = 0.f;
#pragma unroll
    for (int b = 0; b < 8; ++b) {
        s += partials[g4 * 8 + b];
        q += partials[32 + g4 * 8 + b];
    }
    const float inv = 1.f / (8.f * NPTS);
    const float mu = s * inv;
    const float rs = rsqrtf(q * inv - mu * mu + EPSV);
    const float alpha = rs * gw[h];
    const float gamma = fmaf(-mu, alpha, gb[h]);
    float freg[16];
#pragma unroll
    for (int r = 0; r < 16; ++r) {
        const int jr = (r & 3) + 8 * (r >> 2) + 4 * khalf;  /* D row for reg r */
        freg[r] = fmaf(traw[(jt0 + jr) * HDIM + h], alpha, gamma);
    }

    f32x16 czero;
#pragma unroll
    for (int e = 0; e < 16; ++e) czero[e] = 0.f;

    __syncthreads();

/* load one i's pack into named register buffers (wave-uniform -> s_load) */
#define LOADI(M, G0, G1, il) do {                                             \
        const float4* ip4 = (const float4*)(ipack + (ibase + (il)) * IPK);    \
        M[0] = ip4[0]; M[1] = ip4[1]; M[2] = ip4[2]; M[3] = ip4[3];           \
        M[4] = ip4[4]; M[5] = ip4[5]; M[6] = ip4[6]; M[7] = ip4[7];           \
        G0 = ip4[8]; G1 = ip4[9];                                             \
    } while (0)

/* one (i, 32j-tile) step: geometry + U pack + MFMA + f-weighted j-reduce */
#define BODY(M, G0, G1, il) do {                                              \
        const float dx = pjx - G0.x, dy = pjy - G0.y, dz = pjz - G0.z;        \
        const float sq = fmaf(dx, dx, fmaf(dy, dy, dz * dz));                 \
        const float dt = fmaf(G0.w, njx, fmaf(G1.x, njy, G1.y * njz));        \
        const float tt = 2.f - dt;                                            \
        const float wv = __expf(-sq * tt * tt);                               \
        float u[8];                                                           \
        _Pragma("unroll")                                                     \
        for (int c = 0; c < 8; ++c) {                                         \
            const float cut = fmaf(M[c].x, dx, fmaf(M[c].y, dy,               \
                              fmaf(M[c].z, dz, M[c].w)));                     \
            u[c] = wv * fmaxf(cut, 0.f);                                      \
        }                                                                     \
        bf16x8 afrag;                                                         \
        afrag[0] = (__bf16)(khalf == 0 ? u[0] : wv);                          \
        _Pragma("unroll")                                                     \
        for (int e = 1; e < 8; ++e)                                           \
            afrag[e] = (__bf16)(khalf == 0 ? u[e] : 0.f);                     \
        const f32x16 d = __builtin_amdgcn_mfma_f32_32x32x16_bf16(             \
            afrag, bfrag, czero, 0, 0, 0);                                    \
        float p0 = 0.f, p1 = 0.f, p2 = 0.f, p3 = 0.f;                         \
        _Pragma("unroll")                                                     \
        for (int r = 0; r < 16; r += 4) {                                     \
            p0 = fmaf(fmaxf(d[r],     0.f), freg[r],     p0);                 \
            p1 = fmaf(fmaxf(d[r + 1], 0.f), freg[r + 1], p1);                 \
            p2 = fmaf(fmaxf(d[r + 2], 0.f), freg[r + 2], p2);                 \
            p3 = fmaf(fmaxf(d[r + 3], 0.f), freg[r + 3], p3);                 \
        }                                                                     \
        atomicAdd(&sacc[il][h], (p0 + p1) + (p2 + p3));                       \
    } while (0)

    /* ---- 2-deep pipelined i-loop (unroll 1: bounds the s_load window) ---- */
    float4 MA[8], MB[8], GA0, GA1, GB0, GB1;
    LOADI(MA, GA0, GA1, 0);
#pragma unroll 1
    for (int ii = 0; ii < ICH; ii += 2) {
        LOADI(MB, GB0, GB1, ii + 1);
        BODY(MA, GA0, GA1, ii);
        if (ii + 2 < ICH) LOADI(MA, GA0, GA1, ii + 2);
        BODY(MB, GB0, GB1, ii + 1);
    }
#undef LOADI
#undef BODY

    __syncthreads();

    /* ---- flush tile to global (512 threads = 512 cells) ---- */
    {
        const int il0 = t >> 5, h0 = t & 31;
        atomicAdd(&fout[(ibase + il0) * HDIM + h0], sacc[il0][h0]);
    }
}

extern "C" void kernel_launch(void* const* d_in, const int* in_sizes, int n_in,
                              void* d_out, int out_size, void* d_ws, size_t ws_size,
                              hipStream_t stream)
{
    const float* points   = (const float*)d_in[0];
    const float* nuv      = (const float*)d_in[1];
    const float* features = (const float*)d_in[2];
    const float* W_in1    = (const float*)d_in[3];
    const float* b_in1    = (const float*)d_in[4];
    const float* W_in2    = (const float*)d_in[5];
    const float* b_in2    = (const float*)d_in[6];
    const float* g_in_w   = (const float*)d_in[7];
    const float* g_in_b   = (const float*)d_in[8];
    const float* A1       = (const float*)d_in[9];
    const float* A2       = (const float*)d_in[10];
    const float* W_out1   = (const float*)d_in[11];
    const float* b_out1   = (const float*)d_in[12];
    const float* W_out2   = (const float*)d_in[13];
    const float* b_out2   = (const float*)d_in[14];
    const float* g_out_w  = (const float*)d_in[15];
    const float* g_out_b  = (const float*)d_in[16];
    const float* B1       = (const float*)d_in[17];
    const float* B2       = (const float*)d_in[18];

    float* ws    = (float*)d_ws;
    float* t2a   = ws;               /* N*H raw net_in output */
    float* t2b   = ws + 65536;       /* N*H raw net_out output */
    float* fout  = ws + 131072;      /* N*H pairwise accumulator */
    float* ipack = ws + 196608;      /* N*IPK = 98304 */
    float* part1 = ws + 294912;      /* 64 floats */
    float* part2 = ws + 294976;      /* 64 floats */
    float* out   = (float*)d_out;

    /* net_in (+stats partials, +zero fout, +ipack) */
    net2_kernel<IDIM><<<dim3(NPTS / 256), dim3(256), 0, stream>>>(
        features, W_in1, b_in1, W_in2, b_in2, t2a, part1, fout,
        points, nuv, A1, B1, ipack);

    /* all-pairs interaction (GroupNorm of f applied on the fly) */
    pairwise_kernel<<<dim3(NPTS / 256, NPTS / ICH), dim3(512), 0, stream>>>(
        points, nuv, A2, B2, ipack, t2a, part1, g_in_w, g_in_b, fout);

    /* net_out (+stats partials), then final normalize -> out */
    net2_kernel<HDIM><<<dim3(NPTS / 256), dim3(256), 0, stream>>>(
        fout, W_out1, b_out1, W_out2, b_out2, t2b, part2, nullptr,
        nullptr, nullptr, nullptr, nullptr, nullptr);
    gn_apply_kernel<<<dim3(NPTS * HDIM / 256), dim3(256), 0, stream>>>(
        t2b, part2, g_out_w, g_out_b, out);
}